// Round 8
// baseline (195.006 us; speedup 1.0000x reference)
//
#include <hip/hip_runtime.h>
#include <math.h>

// ---------------------------------------------------------------------------
// spline_net r7: scalar-weight (SGPR) gemm + doubled bin parallelism.
//   r6 counters: phase1 70us, occ 28%, VALU 16% — latency bound. Arithmetic
//   showed gemm's LDS weight reads (1536 ds_read_b128/thread, ~18k cyc/wave
//   issue) exceed its 12.3k cyc of FMA. Weights are wave-uniform -> read
//   straight from global with uniform addresses so the compiler emits
//   s_load + v_fma(s,v,v): no LDS, no syncthreads. bin CHUNK 4096->2048.
// N=100000, F_IN=128, HID=16, C=10, E=1600000
// ---------------------------------------------------------------------------

#define SHIFT    7            // 128 nodes per bucket
#define BNODES   128
#define NBUK_MAX 800          // supports N <= 102400
#define CAP      2432         // bucket capacity; mean 2046, sigma ~45 -> +8.5σ
#define CHUNK    2048         // edges per bin block (r7: was 4096)

// ---- fused phase 1: gemm part (no LDS) + bin part ---------------------------

__device__ __forceinline__ void gemm_part(
    int gb, int tid,
    const float* __restrict__ x, const float* __restrict__ W1,
    const float* __restrict__ root1, float* __restrict__ h01,
    float* __restrict__ xr, int N)
{
    int n = gb * 256 + tid;
    if (n >= N) return;

    float acc[48];
#pragma unroll
    for (int j = 0; j < 48; ++j) acc[j] = 0.f;

    const float4* xrow = (const float4*)(x + (size_t)n * 128);
#pragma unroll 2
    for (int k4 = 0; k4 < 32; ++k4) {
        float4 xv = xrow[k4];
#pragma unroll
        for (int kk = 0; kk < 4; ++kk) {
            int k = k4 * 4 + kk;
            float xk = (kk == 0) ? xv.x : (kk == 1) ? xv.y : (kk == 2) ? xv.z : xv.w;
            const float* w0 = W1 + k * 16;          // wave-uniform -> s_load
            const float* w1 = W1 + 2048 + k * 16;   // wave-uniform
            const float* wr = root1 + k * 16;       // wave-uniform
#pragma unroll
            for (int j = 0; j < 16; ++j) {
                acc[j]      += xk * w0[j];
                acc[16 + j] += xk * w1[j];
                acc[32 + j] += xk * wr[j];
            }
        }
    }
    float4* out01 = (float4*)(h01 + (size_t)n * 32);
#pragma unroll
    for (int q = 0; q < 8; ++q)
        out01[q] = make_float4(acc[q * 4], acc[q * 4 + 1], acc[q * 4 + 2], acc[q * 4 + 3]);
    float4* outr = (float4*)(xr + (size_t)n * 16);
#pragma unroll
    for (int q = 0; q < 4; ++q)
        outr[q] = make_float4(acc[32 + q * 4], acc[33 + q * 4], acc[34 + q * 4], acc[35 + q * 4]);
}

__device__ __forceinline__ void bin_part(
    int* __restrict__ smem, int bb, int tid,
    const int* __restrict__ ei, const float* __restrict__ ea,
    int* __restrict__ gcur, int2* __restrict__ staging, int E, int nbuk)
{
    int* bcnt  = smem;                  // NBUK_MAX
    int* gbase = bcnt + NBUK_MAX;       // NBUK_MAX
    for (int i = tid; i < nbuk; i += 256) bcnt[i] = 0;
    __syncthreads();

    int base = bb * CHUNK;
    int lrank[8];
#pragma unroll
    for (int i = 0; i < 8; ++i) {
        int e = base + i * 256 + tid;
        lrank[i] = 0;
        if (e < E) lrank[i] = atomicAdd(&bcnt[ei[E + e] >> SHIFT], 1);
    }
    __syncthreads();
    for (int b = tid; b < nbuk; b += 256) {
        int c = bcnt[b];
        gbase[b] = c ? atomicAdd(&gcur[b], c) : 0;
    }
    __syncthreads();
#pragma unroll
    for (int i = 0; i < 8; ++i) {
        int e = base + i * 256 + tid;
        if (e < E) {
            int s = ei[e];
            int d = ei[E + e];
            int b = d >> SHIFT;
            int p = gbase[b] + lrank[i];
            if (p < CAP)
                staging[(size_t)b * CAP + p] =
                    make_int2(s | ((d & (BNODES - 1)) << 17), __float_as_int(ea[e]));
        }
    }
}

__global__ __launch_bounds__(256) void phase1_kernel(
    const float* __restrict__ x, const float* __restrict__ W1,
    const float* __restrict__ root1, float* __restrict__ h01,
    float* __restrict__ xr,
    const int* __restrict__ ei, const float* __restrict__ ea,
    int* __restrict__ gcur, int2* __restrict__ staging,
    int N, int E, int nbuk, int gemmBlocks)
{
    __shared__ int smem[2 * NBUK_MAX];   // used by bin blocks only (6.4KB)
    int tid = threadIdx.x;
    if ((int)blockIdx.x < gemmBlocks)
        gemm_part(blockIdx.x, tid, x, W1, root1, h01, xr, N);
    else
        bin_part(smem, blockIdx.x - gemmBlocks, tid, ei, ea, gcur, staging, E, nbuk);
}

// In-place per-bucket counting sort (node-sorted CSR inside the bucket).
__global__ __launch_bounds__(256) void csr_build_kernel(
    int2* __restrict__ staging, const int* __restrict__ gcur,
    int* __restrict__ roff, int* __restrict__ cnt,
    float* __restrict__ degf, int N)
{
    __shared__ int2 rin[CAP];
    __shared__ int2 rout[CAP];
    __shared__ int hist[BNODES];
    __shared__ int sscan[BNODES];
    __shared__ int wcur[BNODES];
    int tid = threadIdx.x;
    int b = blockIdx.x;
    int m = gcur[b];
    if (m > CAP) m = CAP;
    int2* sp = staging + (size_t)b * CAP;

    if (tid < BNODES) { hist[tid] = 0; wcur[tid] = 0; }
    __syncthreads();
    for (int k = tid; k < m; k += 256) {
        int2 r = sp[k];
        rin[k] = r;
        atomicAdd(&hist[r.x >> 17], 1);
    }
    __syncthreads();
    if (tid < BNODES) sscan[tid] = hist[tid];
    __syncthreads();
    for (int off = 1; off < BNODES; off <<= 1) {
        int t = (tid < BNODES && tid >= off) ? sscan[tid - off] : 0;
        __syncthreads();
        if (tid < BNODES) sscan[tid] += t;
        __syncthreads();
    }
    for (int k = tid; k < m; k += 256) {
        int2 r = rin[k];
        int dl = r.x >> 17;
        int pos = (sscan[dl] - hist[dl]) + atomicAdd(&wcur[dl], 1);
        rout[pos] = make_int2(r.x & 0x1FFFF, r.y);
    }
    __syncthreads();
    for (int k = tid; k < m; k += 256) sp[k] = rout[k];
    if (tid < BNODES) {
        int n = b * BNODES + tid;
        if (n < N) {
            roff[n] = b * CAP + (sscan[tid] - hist[tid]);
            cnt[n]  = hist[tid];
            degf[n] = (float)hist[tid];
        }
    }
}

// Layer-1 gather: 16 lanes per node, lane c owns channel c.
__global__ __launch_bounds__(256) void gather1_kernel(
    const int2* __restrict__ staging, const int* __restrict__ roff,
    const int* __restrict__ cnt, const float* __restrict__ h01,
    float* __restrict__ agg1, int N)
{
    int t = blockIdx.x * 256 + threadIdx.x;
    int n = t >> 4;
    int c = t & 15;
    if (n >= N) return;
    int start = roff[n];
    int m = cnt[n];
    float acc = 0.f;
#pragma unroll 2
    for (int k = 0; k < m; ++k) {
        int2 r = staging[(size_t)start + k];
        int s = r.x;
        float w = __int_as_float(r.y);
        float a = h01[(size_t)s * 32 + c];
        float bb = h01[(size_t)s * 32 + 16 + c];
        acc += a + w * (bb - a);
    }
    agg1[(size_t)n * 16 + c] = acc;
}

// h = elu(agg1/max(deg,1) + xr + b1), in place over xr; hrb = h@root2 + b2
__global__ __launch_bounds__(256) void finalize1_kernel(
    const float* __restrict__ agg1, const float* __restrict__ degf,
    float* __restrict__ xrh, const float* __restrict__ b1,
    const float* __restrict__ root2, const float* __restrict__ b2,
    float* __restrict__ hrb, int N)
{
    __shared__ float r2s[160];
    __shared__ float b1s[16];
    __shared__ float b2s[10];
    int tid = threadIdx.x;
    if (tid < 160) r2s[tid] = root2[tid];
    if (tid < 16)  b1s[tid] = b1[tid];
    if (tid < 10)  b2s[tid] = b2[tid];
    __syncthreads();
    int n = blockIdx.x * 256 + tid;
    if (n >= N) return;

    float invd = 1.0f / fmaxf(degf[n], 1.0f);
    float hv[16];
#pragma unroll
    for (int c = 0; c < 16; ++c) {
        float v = agg1[(size_t)n * 16 + c] * invd + xrh[(size_t)n * 16 + c] + b1s[c];
        hv[c] = v > 0.f ? v : expm1f(v);
    }
    float4* hp = (float4*)(xrh + (size_t)n * 16);
#pragma unroll
    for (int q = 0; q < 4; ++q)
        hp[q] = make_float4(hv[q * 4], hv[q * 4 + 1], hv[q * 4 + 2], hv[q * 4 + 3]);

    float hr[10];
#pragma unroll
    for (int j = 0; j < 10; ++j) hr[j] = b2s[j];
#pragma unroll
    for (int i = 0; i < 16; ++i)
#pragma unroll
        for (int j = 0; j < 10; ++j)
            hr[j] += hv[i] * r2s[i * 10 + j];
    float* hb = hrb + (size_t)n * 10;
#pragma unroll
    for (int j = 0; j < 10; ++j) hb[j] = hr[j];
}

// Layer-2 gather in h-space: p = sum (1-w)h[src], q = sum w*h[src]
__global__ __launch_bounds__(256) void gather2_kernel(
    const int2* __restrict__ staging, const int* __restrict__ roff,
    const int* __restrict__ cnt, const float* __restrict__ h,
    float* __restrict__ pq, int N)
{
    int t = blockIdx.x * 256 + threadIdx.x;
    int n = t >> 4;
    int c = t & 15;
    if (n >= N) return;
    int start = roff[n];
    int m = cnt[n];
    float p = 0.f, q = 0.f;
#pragma unroll 2
    for (int k = 0; k < m; ++k) {
        int2 r = staging[(size_t)start + k];
        float w = __int_as_float(r.y);
        float v = h[(size_t)r.x * 16 + c];
        p += (1.f - w) * v;
        q += w * v;
    }
    pq[(size_t)n * 32 + c]      = p;
    pq[(size_t)n * 32 + 16 + c] = q;
}

// out = (p@W2[0] + q@W2[1])/max(deg,1) + hrb
__global__ __launch_bounds__(256) void finalize2_kernel(
    const float* __restrict__ pq, const float* __restrict__ degf,
    const float* __restrict__ hrb, const float* __restrict__ W2,
    float* __restrict__ out, int N)
{
    __shared__ float w2s[320];
    int tid = threadIdx.x;
    for (int idx = tid; idx < 320; idx += 256) w2s[idx] = W2[idx];
    __syncthreads();
    int n = blockIdx.x * 256 + tid;
    if (n >= N) return;

    float invd = 1.0f / fmaxf(degf[n], 1.0f);
    float pv[16], qv[16];
    const float4* pp = (const float4*)(pq + (size_t)n * 32);
#pragma unroll
    for (int q4 = 0; q4 < 4; ++q4) {
        float4 a = pp[q4];
        pv[q4 * 4] = a.x; pv[q4 * 4 + 1] = a.y; pv[q4 * 4 + 2] = a.z; pv[q4 * 4 + 3] = a.w;
        float4 bq = pp[4 + q4];
        qv[q4 * 4] = bq.x; qv[q4 * 4 + 1] = bq.y; qv[q4 * 4 + 2] = bq.z; qv[q4 * 4 + 3] = bq.w;
    }
    float o[10];
#pragma unroll
    for (int j = 0; j < 10; ++j) o[j] = 0.f;
#pragma unroll
    for (int i = 0; i < 16; ++i)
#pragma unroll
        for (int j = 0; j < 10; ++j)
            o[j] += pv[i] * w2s[i * 10 + j] + qv[i] * w2s[160 + i * 10 + j];
    float* op = out + (size_t)n * 10;
    const float* hb = hrb + (size_t)n * 10;
#pragma unroll
    for (int j = 0; j < 10; ++j) op[j] = o[j] * invd + hb[j];
}

extern "C" void kernel_launch(void* const* d_in, const int* in_sizes, int n_in,
                              void* d_out, int out_size, void* d_ws, size_t ws_size,
                              hipStream_t stream)
{
    const float* x     = (const float*)d_in[0];
    const int*   ei    = (const int*)d_in[1];   // (2,E)
    const float* ea    = (const float*)d_in[2]; // (E,1)
    const float* W1    = (const float*)d_in[3]; // (2,128,16)
    const float* root1 = (const float*)d_in[4]; // (128,16)
    const float* b1    = (const float*)d_in[5]; // (16,)
    const float* W2    = (const float*)d_in[6]; // (2,16,10)
    const float* root2 = (const float*)d_in[7]; // (16,10)
    const float* b2    = (const float*)d_in[8]; // (10,)
    float* out = (float*)d_out;

    int N = in_sizes[0] / 128;
    int E = in_sizes[2];
    int nbuk = (N + BNODES - 1) / BNODES;   // 782

    // workspace layout unchanged from passing r5/r6 (46.0 MB)
    char* ws = (char*)d_ws;
    int2*  staging = (int2*)ws;
    float* buf32 = (float*)(ws + (size_t)nbuk * CAP * 8);
    float* h01   = buf32;
    float* pq    = buf32;
    float* xrh   = buf32 + (size_t)N * 32;
    float* agg1  = xrh  + (size_t)N * 16;
    float* hrb   = agg1 + (size_t)N * 16;
    float* degf  = hrb  + (size_t)N * 10;
    int*   cnt   = (int*)(degf + N);
    int*   roff  = cnt  + N;
    int*   gcur  = roff + N;

    int nb_n = (N + 255) / 256;
    int nb_e16 = (N * 16 + 255) / 256;
    int gemmBlocks = (N + 255) / 256;                  // 391
    int binBlocks  = (E + CHUNK - 1) / CHUNK;          // 782

    hipMemsetAsync(gcur, 0, (size_t)nbuk * sizeof(int), stream);

    phase1_kernel   <<<gemmBlocks + binBlocks, 256, 0, stream>>>(
        x, W1, root1, h01, xrh, ei, ea, gcur, staging, N, E, nbuk, gemmBlocks);
    csr_build_kernel<<<nbuk, 256, 0, stream>>>(staging, gcur, roff, cnt, degf, N);
    gather1_kernel  <<<nb_e16, 256, 0, stream>>>(staging, roff, cnt, h01, agg1, N);
    finalize1_kernel<<<nb_n, 256, 0, stream>>>(agg1, degf, xrh, b1, root2, b2, hrb, N);
    gather2_kernel  <<<nb_e16, 256, 0, stream>>>(staging, roff, cnt, xrh, pq, N);
    finalize2_kernel<<<nb_n, 256, 0, stream>>>(pq, degf, hrb, W2, out, N);
}

// Round 9
// 170.156 us; speedup vs baseline: 1.1460x; 1.1460x over previous
//
#include <hip/hip_runtime.h>
#include <math.h>

// ---------------------------------------------------------------------------
// spline_net r8: wave-uniform scalar-weight gemm (forced via readfirstlane) +
// interleaved gemm/bin block mix.
//   r7 post-mortem: scalar gemm spilled (VGPR_Count 44 < acc[48]) -> scratch
//   traffic (FETCH 43->62MB), phase1 107us. Fix: half-split by WAVE (not by
//   lane parity): half = readfirstlane(wid&1) makes weight pointers provably
//   wave-uniform -> s_load + v_fma(v,s,v); acc[24] leaves regalloc headroom.
//   gemm/bin blocks interleaved by blockIdx parity for co-residency.
// N=100000, F_IN=128, HID=16, C=10, E=1600000
// ---------------------------------------------------------------------------

#define SHIFT    7            // 128 nodes per bucket
#define BNODES   128
#define NBUK_MAX 800          // supports N <= 102400
#define CAP      2432         // bucket capacity; mean 2046, sigma ~45 -> +8.5σ
#define CHUNK    2048         // edges per bin block

// ---- gemm: one wave computes 24 cols for 64 nodes; weights via s_load ------

template<int LA, int LB>
__device__ __forceinline__ void gemm_halfT(
    const float4* __restrict__ xrow,
    const float* __restrict__ WA, const float* __restrict__ WB,
    float* __restrict__ acc)
{
#pragma unroll 2
    for (int k4 = 0; k4 < 32; ++k4) {
        float4 xv = xrow[k4];
        float xs[4] = {xv.x, xv.y, xv.z, xv.w};
#pragma unroll
        for (int kk = 0; kk < 4; ++kk) {
            int k = k4 * 4 + kk;
            float xk = xs[kk];
#pragma unroll
            for (int j = 0; j < LA; ++j) acc[j] += xk * WA[k * 16 + j];
#pragma unroll
            for (int j = 0; j < LB; ++j) acc[LA + j] += xk * WB[k * 16 + j];
        }
    }
}

__device__ __forceinline__ void gemm_part(
    int gb, int tid,
    const float* __restrict__ x, const float* __restrict__ W1,
    const float* __restrict__ root1, float* __restrict__ h01,
    float* __restrict__ xr, int N)
{
    int wid  = tid >> 6;                                   // 0..3
    int lane = tid & 63;
    int half = __builtin_amdgcn_readfirstlane(wid & 1);    // wave-uniform 0/1
    int nl   = (wid >> 1) * 64 + lane;                     // 0..127
    int n = gb * 128 + nl;
    if (n >= N) return;

    float acc[24];
#pragma unroll
    for (int j = 0; j < 24; ++j) acc[j] = 0.f;

    const float4* xrow = (const float4*)(x + (size_t)n * 128);
    // flat col c of the 48-wide output:
    //   c in [0,16):  W1[k*16+c]         (W1[0])
    //   c in [16,32): W1[2048+k*16+c-16] (W1[1])
    //   c in [32,48): root1[k*16+c-32]
    if (half == 0) {
        // cols 0..23 = W1[0][k][0:16] ++ W1[1][k][0:8]
        gemm_halfT<16, 8>(xrow, W1, W1 + 2048, acc);
        float4* out01 = (float4*)(h01 + (size_t)n * 32);
#pragma unroll
        for (int q = 0; q < 6; ++q)
            out01[q] = make_float4(acc[q * 4], acc[q * 4 + 1], acc[q * 4 + 2], acc[q * 4 + 3]);
    } else {
        // cols 24..47 = W1[1][k][8:16] ++ root1[k][0:16]
        gemm_halfT<8, 16>(xrow, W1 + 2048 + 8, root1, acc);
        float4* out01 = (float4*)(h01 + (size_t)n * 32);
#pragma unroll
        for (int q = 0; q < 2; ++q)
            out01[6 + q] = make_float4(acc[q * 4], acc[q * 4 + 1], acc[q * 4 + 2], acc[q * 4 + 3]);
        float4* outr = (float4*)(xr + (size_t)n * 16);
#pragma unroll
        for (int q = 0; q < 4; ++q)
            outr[q] = make_float4(acc[8 + q * 4], acc[9 + q * 4], acc[10 + q * 4], acc[11 + q * 4]);
    }
}

__device__ __forceinline__ void bin_part(
    int* __restrict__ smem, int bb, int tid,
    const int* __restrict__ ei, const float* __restrict__ ea,
    int* __restrict__ gcur, int2* __restrict__ staging, int E, int nbuk)
{
    int* bcnt  = smem;                  // NBUK_MAX
    int* gbase = bcnt + NBUK_MAX;       // NBUK_MAX
    for (int i = tid; i < nbuk; i += 256) bcnt[i] = 0;
    __syncthreads();

    int base = bb * CHUNK;
    int lrank[8];
#pragma unroll
    for (int i = 0; i < 8; ++i) {
        int e = base + i * 256 + tid;
        lrank[i] = 0;
        if (e < E) lrank[i] = atomicAdd(&bcnt[ei[E + e] >> SHIFT], 1);
    }
    __syncthreads();
    for (int b = tid; b < nbuk; b += 256) {
        int c = bcnt[b];
        gbase[b] = c ? atomicAdd(&gcur[b], c) : 0;
    }
    __syncthreads();
#pragma unroll
    for (int i = 0; i < 8; ++i) {
        int e = base + i * 256 + tid;
        if (e < E) {
            int s = ei[e];
            int d = ei[E + e];
            int b = d >> SHIFT;
            int p = gbase[b] + lrank[i];
            if (p < CAP)
                staging[(size_t)b * CAP + p] =
                    make_int2(s | ((d & (BNODES - 1)) << 17), __float_as_int(ea[e]));
        }
    }
}

// even blockIdx -> gemm block (bid>>1), odd -> bin block (bid>>1)
__global__ __launch_bounds__(256) void phase1_kernel(
    const float* __restrict__ x, const float* __restrict__ W1,
    const float* __restrict__ root1, float* __restrict__ h01,
    float* __restrict__ xr,
    const int* __restrict__ ei, const float* __restrict__ ea,
    int* __restrict__ gcur, int2* __restrict__ staging,
    int N, int E, int nbuk, int gemmBlocks)
{
    __shared__ int smem[2 * NBUK_MAX];   // used by bin blocks only (6.4KB)
    int tid = threadIdx.x;
    int bid = blockIdx.x;
    int sub = bid >> 1;
    if ((bid & 1) == 0) {
        if (sub < gemmBlocks) gemm_part(sub, tid, x, W1, root1, h01, xr, N);
    } else {
        bin_part(smem, sub, tid, ei, ea, gcur, staging, E, nbuk);
    }
}

// In-place per-bucket counting sort (node-sorted CSR inside the bucket).
__global__ __launch_bounds__(256) void csr_build_kernel(
    int2* __restrict__ staging, const int* __restrict__ gcur,
    int* __restrict__ roff, int* __restrict__ cnt,
    float* __restrict__ degf, int N)
{
    __shared__ int2 rin[CAP];
    __shared__ int2 rout[CAP];
    __shared__ int hist[BNODES];
    __shared__ int sscan[BNODES];
    __shared__ int wcur[BNODES];
    int tid = threadIdx.x;
    int b = blockIdx.x;
    int m = gcur[b];
    if (m > CAP) m = CAP;
    int2* sp = staging + (size_t)b * CAP;

    if (tid < BNODES) { hist[tid] = 0; wcur[tid] = 0; }
    __syncthreads();
    for (int k = tid; k < m; k += 256) {
        int2 r = sp[k];
        rin[k] = r;
        atomicAdd(&hist[r.x >> 17], 1);
    }
    __syncthreads();
    if (tid < BNODES) sscan[tid] = hist[tid];
    __syncthreads();
    for (int off = 1; off < BNODES; off <<= 1) {
        int t = (tid < BNODES && tid >= off) ? sscan[tid - off] : 0;
        __syncthreads();
        if (tid < BNODES) sscan[tid] += t;
        __syncthreads();
    }
    for (int k = tid; k < m; k += 256) {
        int2 r = rin[k];
        int dl = r.x >> 17;
        int pos = (sscan[dl] - hist[dl]) + atomicAdd(&wcur[dl], 1);
        rout[pos] = make_int2(r.x & 0x1FFFF, r.y);
    }
    __syncthreads();
    for (int k = tid; k < m; k += 256) sp[k] = rout[k];
    if (tid < BNODES) {
        int n = b * BNODES + tid;
        if (n < N) {
            roff[n] = b * CAP + (sscan[tid] - hist[tid]);
            cnt[n]  = hist[tid];
            degf[n] = (float)hist[tid];
        }
    }
}

// Layer-1 gather: 16 lanes per node, lane c owns channel c.
__global__ __launch_bounds__(256) void gather1_kernel(
    const int2* __restrict__ staging, const int* __restrict__ roff,
    const int* __restrict__ cnt, const float* __restrict__ h01,
    float* __restrict__ agg1, int N)
{
    int t = blockIdx.x * 256 + threadIdx.x;
    int n = t >> 4;
    int c = t & 15;
    if (n >= N) return;
    int start = roff[n];
    int m = cnt[n];
    float acc = 0.f;
#pragma unroll 2
    for (int k = 0; k < m; ++k) {
        int2 r = staging[(size_t)start + k];
        int s = r.x;
        float w = __int_as_float(r.y);
        float a = h01[(size_t)s * 32 + c];
        float bb = h01[(size_t)s * 32 + 16 + c];
        acc += a + w * (bb - a);
    }
    agg1[(size_t)n * 16 + c] = acc;
}

// h = elu(agg1/max(deg,1) + xr + b1), in place over xr; hrb = h@root2 + b2
__global__ __launch_bounds__(256) void finalize1_kernel(
    const float* __restrict__ agg1, const float* __restrict__ degf,
    float* __restrict__ xrh, const float* __restrict__ b1,
    const float* __restrict__ root2, const float* __restrict__ b2,
    float* __restrict__ hrb, int N)
{
    __shared__ float r2s[160];
    __shared__ float b1s[16];
    __shared__ float b2s[10];
    int tid = threadIdx.x;
    if (tid < 160) r2s[tid] = root2[tid];
    if (tid < 16)  b1s[tid] = b1[tid];
    if (tid < 10)  b2s[tid] = b2[tid];
    __syncthreads();
    int n = blockIdx.x * 256 + tid;
    if (n >= N) return;

    float invd = 1.0f / fmaxf(degf[n], 1.0f);
    float hv[16];
#pragma unroll
    for (int c = 0; c < 16; ++c) {
        float v = agg1[(size_t)n * 16 + c] * invd + xrh[(size_t)n * 16 + c] + b1s[c];
        hv[c] = v > 0.f ? v : expm1f(v);
    }
    float4* hp = (float4*)(xrh + (size_t)n * 16);
#pragma unroll
    for (int q = 0; q < 4; ++q)
        hp[q] = make_float4(hv[q * 4], hv[q * 4 + 1], hv[q * 4 + 2], hv[q * 4 + 3]);

    float hr[10];
#pragma unroll
    for (int j = 0; j < 10; ++j) hr[j] = b2s[j];
#pragma unroll
    for (int i = 0; i < 16; ++i)
#pragma unroll
        for (int j = 0; j < 10; ++j)
            hr[j] += hv[i] * r2s[i * 10 + j];
    float* hb = hrb + (size_t)n * 10;
#pragma unroll
    for (int j = 0; j < 10; ++j) hb[j] = hr[j];
}

// Layer-2 gather in h-space: p = sum (1-w)h[src], q = sum w*h[src]
__global__ __launch_bounds__(256) void gather2_kernel(
    const int2* __restrict__ staging, const int* __restrict__ roff,
    const int* __restrict__ cnt, const float* __restrict__ h,
    float* __restrict__ pq, int N)
{
    int t = blockIdx.x * 256 + threadIdx.x;
    int n = t >> 4;
    int c = t & 15;
    if (n >= N) return;
    int start = roff[n];
    int m = cnt[n];
    float p = 0.f, q = 0.f;
#pragma unroll 2
    for (int k = 0; k < m; ++k) {
        int2 r = staging[(size_t)start + k];
        float w = __int_as_float(r.y);
        float v = h[(size_t)r.x * 16 + c];
        p += (1.f - w) * v;
        q += w * v;
    }
    pq[(size_t)n * 32 + c]      = p;
    pq[(size_t)n * 32 + 16 + c] = q;
}

// out = (p@W2[0] + q@W2[1])/max(deg,1) + hrb
__global__ __launch_bounds__(256) void finalize2_kernel(
    const float* __restrict__ pq, const float* __restrict__ degf,
    const float* __restrict__ hrb, const float* __restrict__ W2,
    float* __restrict__ out, int N)
{
    __shared__ float w2s[320];
    int tid = threadIdx.x;
    for (int idx = tid; idx < 320; idx += 256) w2s[idx] = W2[idx];
    __syncthreads();
    int n = blockIdx.x * 256 + tid;
    if (n >= N) return;

    float invd = 1.0f / fmaxf(degf[n], 1.0f);
    float pv[16], qv[16];
    const float4* pp = (const float4*)(pq + (size_t)n * 32);
#pragma unroll
    for (int q4 = 0; q4 < 4; ++q4) {
        float4 a = pp[q4];
        pv[q4 * 4] = a.x; pv[q4 * 4 + 1] = a.y; pv[q4 * 4 + 2] = a.z; pv[q4 * 4 + 3] = a.w;
        float4 bq = pp[4 + q4];
        qv[q4 * 4] = bq.x; qv[q4 * 4 + 1] = bq.y; qv[q4 * 4 + 2] = bq.z; qv[q4 * 4 + 3] = bq.w;
    }
    float o[10];
#pragma unroll
    for (int j = 0; j < 10; ++j) o[j] = 0.f;
#pragma unroll
    for (int i = 0; i < 16; ++i)
#pragma unroll
        for (int j = 0; j < 10; ++j)
            o[j] += pv[i] * w2s[i * 10 + j] + qv[i] * w2s[160 + i * 10 + j];
    float* op = out + (size_t)n * 10;
    const float* hb = hrb + (size_t)n * 10;
#pragma unroll
    for (int j = 0; j < 10; ++j) op[j] = o[j] * invd + hb[j];
}

extern "C" void kernel_launch(void* const* d_in, const int* in_sizes, int n_in,
                              void* d_out, int out_size, void* d_ws, size_t ws_size,
                              hipStream_t stream)
{
    const float* x     = (const float*)d_in[0];
    const int*   ei    = (const int*)d_in[1];   // (2,E)
    const float* ea    = (const float*)d_in[2]; // (E,1)
    const float* W1    = (const float*)d_in[3]; // (2,128,16)
    const float* root1 = (const float*)d_in[4]; // (128,16)
    const float* b1    = (const float*)d_in[5]; // (16,)
    const float* W2    = (const float*)d_in[6]; // (2,16,10)
    const float* root2 = (const float*)d_in[7]; // (16,10)
    const float* b2    = (const float*)d_in[8]; // (10,)
    float* out = (float*)d_out;

    int N = in_sizes[0] / 128;
    int E = in_sizes[2];
    int nbuk = (N + BNODES - 1) / BNODES;   // 782

    // workspace layout unchanged from passing r5/r6/r7 (46.0 MB)
    char* ws = (char*)d_ws;
    int2*  staging = (int2*)ws;
    float* buf32 = (float*)(ws + (size_t)nbuk * CAP * 8);
    float* h01   = buf32;
    float* pq    = buf32;
    float* xrh   = buf32 + (size_t)N * 32;
    float* agg1  = xrh  + (size_t)N * 16;
    float* hrb   = agg1 + (size_t)N * 16;
    float* degf  = hrb  + (size_t)N * 10;
    int*   cnt   = (int*)(degf + N);
    int*   roff  = cnt  + N;
    int*   gcur  = roff + N;

    int nb_n = (N + 255) / 256;
    int nb_e16 = (N * 16 + 255) / 256;
    int gemmBlocks = (N + 127) / 128;                  // 782
    int binBlocks  = (E + CHUNK - 1) / CHUNK;          // 782
    int mixBlocks  = 2 * max(gemmBlocks, binBlocks);   // interleaved even/odd

    hipMemsetAsync(gcur, 0, (size_t)nbuk * sizeof(int), stream);

    phase1_kernel   <<<mixBlocks, 256, 0, stream>>>(
        x, W1, root1, h01, xrh, ei, ea, gcur, staging, N, E, nbuk, gemmBlocks);
    csr_build_kernel<<<nbuk, 256, 0, stream>>>(staging, gcur, roff, cnt, degf, N);
    gather1_kernel  <<<nb_e16, 256, 0, stream>>>(staging, roff, cnt, h01, agg1, N);
    finalize1_kernel<<<nb_n, 256, 0, stream>>>(agg1, degf, xrh, b1, root2, b2, hrb, N);
    gather2_kernel  <<<nb_e16, 256, 0, stream>>>(staging, roff, cnt, xrh, pq, N);
    finalize2_kernel<<<nb_n, 256, 0, stream>>>(pq, degf, hrb, W2, out, N);
}

// Round 10
// 158.222 us; speedup vs baseline: 1.2325x; 1.0754x over previous
//
#include <hip/hip_runtime.h>
#include <math.h>

// ---------------------------------------------------------------------------
// spline_net r9: revert gemm to the r6 LDS form (scalar-weight SGPR gemm
// spilled twice: r7 VGPR=44, r8 VGPR=20 — regalloc caps kill acc arrays),
// with float4 weight reads + permuted columns; NEW: bf16-packed gather
// tables. gather1 reads ONE uint (h0,h1 pair) per lane per edge -> 102MB
// instead of 205MB; h table bf16 (3.2MB, ~L2-resident) for gather2.
// N=100000, F_IN=128, HID=16, C=10, E=1600000
// ---------------------------------------------------------------------------

#define SHIFT    7            // 128 nodes per bucket
#define BNODES   128
#define NBUK_MAX 800          // supports N <= 102400
#define CAP      2432         // bucket capacity; mean 2046, sigma ~45 -> +8.5σ
#define CHUNK    2048         // edges per bin block

__device__ __forceinline__ unsigned short f2bf(float f) {
    unsigned int u = __float_as_uint(f);
    u += 0x7FFF + ((u >> 16) & 1);        // round to nearest even
    return (unsigned short)(u >> 16);
}

// ---- fused phase 1: gemm part (LDS weights, permuted cols) + bin part ------
// LDS col order j' (per k): [0:8)=W1[0][:,0:8)  [8:16)=W1[1][:,0:8)
//   [16:24)=root1[:,0:8)  [24:32)=W1[0][:,8:16) [32:40)=W1[1][:,8:16)
//   [40:48)=root1[:,8:16)
// half0 owns cols 0..23 (h0/h1/xr ch 0-7), half1 cols 24..47 (ch 8-15).

__device__ __forceinline__ void gemm_part(
    float* __restrict__ Ws, int gb, int tid,
    const float* __restrict__ x, const float* __restrict__ W1,
    const float* __restrict__ root1, unsigned int* __restrict__ h01i,
    float* __restrict__ xr, int N)
{
    for (int idx = tid; idx < 128 * 48; idx += 256) {
        int k = idx / 48, j = idx % 48;
        int grp = j >> 3, t = j & 7;
        float v;
        switch (grp) {
            case 0: v = W1[k * 16 + t];            break;
            case 1: v = W1[2048 + k * 16 + t];     break;
            case 2: v = root1[k * 16 + t];         break;
            case 3: v = W1[k * 16 + 8 + t];        break;
            case 4: v = W1[2048 + k * 16 + 8 + t]; break;
            default: v = root1[k * 16 + 8 + t];    break;
        }
        Ws[idx] = v;
    }
    __syncthreads();
    int nl   = tid >> 1;          // node within block
    int half = tid & 1;           // channel group 0-7 / 8-15
    int n = gb * 128 + nl;
    if (n >= N) return;

    float acc[24];
#pragma unroll
    for (int j = 0; j < 24; ++j) acc[j] = 0.f;

    const float4* xrow = (const float4*)(x + (size_t)n * 128);
    const float4* wbase = (const float4*)(Ws + half * 24);   // 96B offset, 16B-aligned
#pragma unroll 2
    for (int k4 = 0; k4 < 32; ++k4) {
        float4 xv = xrow[k4];
        float xs[4] = {xv.x, xv.y, xv.z, xv.w};
#pragma unroll
        for (int kk = 0; kk < 4; ++kk) {
            float xk = xs[kk];
            const float4* w4 = wbase + ((k4 * 4 + kk) * 48) / 4;  // row k, 12 float4s/row
#pragma unroll
            for (int q = 0; q < 6; ++q) {
                float4 wv = w4[q];
                acc[q * 4 + 0] += xk * wv.x;
                acc[q * 4 + 1] += xk * wv.y;
                acc[q * 4 + 2] += xk * wv.z;
                acc[q * 4 + 3] += xk * wv.w;
            }
        }
    }
    // acc[0..7]=h0[ch], acc[8..15]=h1[ch], acc[16..23]=xr[ch], ch=half*8+t
    int cb = half * 8;
#pragma unroll
    for (int t = 0; t < 8; ++t)
        h01i[(size_t)n * 16 + cb + t] =
            (unsigned int)f2bf(acc[t]) | ((unsigned int)f2bf(acc[8 + t]) << 16);
#pragma unroll
    for (int t = 0; t < 8; ++t)
        xr[(size_t)n * 16 + cb + t] = acc[16 + t];
}

__device__ __forceinline__ void bin_part(
    int* __restrict__ smem, int bb, int tid,
    const int* __restrict__ ei, const float* __restrict__ ea,
    int* __restrict__ gcur, int2* __restrict__ staging, int E, int nbuk)
{
    int* bcnt  = smem;                  // NBUK_MAX
    int* gbase = bcnt + NBUK_MAX;       // NBUK_MAX
    for (int i = tid; i < nbuk; i += 256) bcnt[i] = 0;
    __syncthreads();

    int base = bb * CHUNK;
    int lrank[8];
#pragma unroll
    for (int i = 0; i < 8; ++i) {
        int e = base + i * 256 + tid;
        lrank[i] = 0;
        if (e < E) lrank[i] = atomicAdd(&bcnt[ei[E + e] >> SHIFT], 1);
    }
    __syncthreads();
    for (int b = tid; b < nbuk; b += 256) {
        int c = bcnt[b];
        gbase[b] = c ? atomicAdd(&gcur[b], c) : 0;
    }
    __syncthreads();
#pragma unroll
    for (int i = 0; i < 8; ++i) {
        int e = base + i * 256 + tid;
        if (e < E) {
            int s = ei[e];
            int d = ei[E + e];
            int b = d >> SHIFT;
            int p = gbase[b] + lrank[i];
            if (p < CAP)
                staging[(size_t)b * CAP + p] =
                    make_int2(s | ((d & (BNODES - 1)) << 17), __float_as_int(ea[e]));
        }
    }
}

// even blockIdx -> gemm block, odd -> bin block
__global__ __launch_bounds__(256) void phase1_kernel(
    const float* __restrict__ x, const float* __restrict__ W1,
    const float* __restrict__ root1, unsigned int* __restrict__ h01i,
    float* __restrict__ xr,
    const int* __restrict__ ei, const float* __restrict__ ea,
    int* __restrict__ gcur, int2* __restrict__ staging,
    int N, int E, int nbuk, int gemmBlocks)
{
    __shared__ float smem[128 * 48];   // gemm Ws (24.6KB) | bin counters (6.4KB)
    int tid = threadIdx.x;
    int bid = blockIdx.x;
    int sub = bid >> 1;
    if ((bid & 1) == 0) {
        if (sub < gemmBlocks)
            gemm_part(smem, sub, tid, x, W1, root1, h01i, xr, N);
    } else {
        bin_part((int*)smem, sub, tid, ei, ea, gcur, staging, E, nbuk);
    }
}

// In-place per-bucket counting sort (node-sorted CSR inside the bucket).
__global__ __launch_bounds__(256) void csr_build_kernel(
    int2* __restrict__ staging, const int* __restrict__ gcur,
    int* __restrict__ roff, int* __restrict__ cnt,
    float* __restrict__ degf, int N)
{
    __shared__ int2 rin[CAP];
    __shared__ int2 rout[CAP];
    __shared__ int hist[BNODES];
    __shared__ int sscan[BNODES];
    __shared__ int wcur[BNODES];
    int tid = threadIdx.x;
    int b = blockIdx.x;
    int m = gcur[b];
    if (m > CAP) m = CAP;
    int2* sp = staging + (size_t)b * CAP;

    if (tid < BNODES) { hist[tid] = 0; wcur[tid] = 0; }
    __syncthreads();
    for (int k = tid; k < m; k += 256) {
        int2 r = sp[k];
        rin[k] = r;
        atomicAdd(&hist[r.x >> 17], 1);
    }
    __syncthreads();
    if (tid < BNODES) sscan[tid] = hist[tid];
    __syncthreads();
    for (int off = 1; off < BNODES; off <<= 1) {
        int t = (tid < BNODES && tid >= off) ? sscan[tid - off] : 0;
        __syncthreads();
        if (tid < BNODES) sscan[tid] += t;
        __syncthreads();
    }
    for (int k = tid; k < m; k += 256) {
        int2 r = rin[k];
        int dl = r.x >> 17;
        int pos = (sscan[dl] - hist[dl]) + atomicAdd(&wcur[dl], 1);
        rout[pos] = make_int2(r.x & 0x1FFFF, r.y);
    }
    __syncthreads();
    for (int k = tid; k < m; k += 256) sp[k] = rout[k];
    if (tid < BNODES) {
        int n = b * BNODES + tid;
        if (n < N) {
            roff[n] = b * CAP + (sscan[tid] - hist[tid]);
            cnt[n]  = hist[tid];
            degf[n] = (float)hist[tid];
        }
    }
}

// Layer-1 gather: 16 lanes/node; ONE packed uint (h0,h1 bf16) per lane/edge.
__global__ __launch_bounds__(256) void gather1_kernel(
    const int2* __restrict__ staging, const int* __restrict__ roff,
    const int* __restrict__ cnt, const unsigned int* __restrict__ h01i,
    float* __restrict__ agg1, int N)
{
    int t = blockIdx.x * 256 + threadIdx.x;
    int n = t >> 4;
    int c = t & 15;
    if (n >= N) return;
    int start = roff[n];
    int m = cnt[n];
    float acc = 0.f;
#pragma unroll 2
    for (int k = 0; k < m; ++k) {
        int2 r = staging[(size_t)start + k];
        float w = __int_as_float(r.y);
        unsigned int v = h01i[(size_t)r.x * 16 + c];
        float a  = __uint_as_float(v << 16);            // h0 (lo bf16)
        float bb = __uint_as_float(v & 0xFFFF0000u);    // h1 (hi bf16)
        acc += a + w * (bb - a);
    }
    agg1[(size_t)n * 16 + c] = acc;
}

// h = elu(agg1/max(deg,1) + xr + b1) -> bf16 table hb; hrb = h@root2 + b2
__global__ __launch_bounds__(256) void finalize1_kernel(
    const float* __restrict__ agg1, const float* __restrict__ degf,
    const float* __restrict__ xr, const float* __restrict__ b1,
    const float* __restrict__ root2, const float* __restrict__ b2,
    unsigned short* __restrict__ hb, float* __restrict__ hrb, int N)
{
    __shared__ float r2s[160];
    __shared__ float b1s[16];
    __shared__ float b2s[10];
    int tid = threadIdx.x;
    if (tid < 160) r2s[tid] = root2[tid];
    if (tid < 16)  b1s[tid] = b1[tid];
    if (tid < 10)  b2s[tid] = b2[tid];
    __syncthreads();
    int n = blockIdx.x * 256 + tid;
    if (n >= N) return;

    float invd = 1.0f / fmaxf(degf[n], 1.0f);
    float hv[16];
#pragma unroll
    for (int c = 0; c < 16; ++c) {
        float v = agg1[(size_t)n * 16 + c] * invd + xr[(size_t)n * 16 + c] + b1s[c];
        hv[c] = v > 0.f ? v : expm1f(v);
    }
#pragma unroll
    for (int c = 0; c < 16; ++c) hb[(size_t)n * 16 + c] = f2bf(hv[c]);

    float hr[10];
#pragma unroll
    for (int j = 0; j < 10; ++j) hr[j] = b2s[j];
#pragma unroll
    for (int i = 0; i < 16; ++i)
#pragma unroll
        for (int j = 0; j < 10; ++j)
            hr[j] += hv[i] * r2s[i * 10 + j];
    float* hp = hrb + (size_t)n * 10;
#pragma unroll
    for (int j = 0; j < 10; ++j) hp[j] = hr[j];
}

// Layer-2 gather in h-space (bf16 table): p = sum (1-w)h, q = sum w*h
__global__ __launch_bounds__(256) void gather2_kernel(
    const int2* __restrict__ staging, const int* __restrict__ roff,
    const int* __restrict__ cnt, const unsigned short* __restrict__ hb,
    float* __restrict__ pq, int N)
{
    int t = blockIdx.x * 256 + threadIdx.x;
    int n = t >> 4;
    int c = t & 15;
    if (n >= N) return;
    int start = roff[n];
    int m = cnt[n];
    float p = 0.f, q = 0.f;
#pragma unroll 2
    for (int k = 0; k < m; ++k) {
        int2 r = staging[(size_t)start + k];
        float w = __int_as_float(r.y);
        float v = __uint_as_float(((unsigned int)hb[(size_t)r.x * 16 + c]) << 16);
        p += (1.f - w) * v;
        q += w * v;
    }
    pq[(size_t)n * 32 + c]      = p;
    pq[(size_t)n * 32 + 16 + c] = q;
}

// out = (p@W2[0] + q@W2[1])/max(deg,1) + hrb
__global__ __launch_bounds__(256) void finalize2_kernel(
    const float* __restrict__ pq, const float* __restrict__ degf,
    const float* __restrict__ hrb, const float* __restrict__ W2,
    float* __restrict__ out, int N)
{
    __shared__ float w2s[320];
    int tid = threadIdx.x;
    for (int idx = tid; idx < 320; idx += 256) w2s[idx] = W2[idx];
    __syncthreads();
    int n = blockIdx.x * 256 + tid;
    if (n >= N) return;

    float invd = 1.0f / fmaxf(degf[n], 1.0f);
    float pv[16], qv[16];
    const float4* pp = (const float4*)(pq + (size_t)n * 32);
#pragma unroll
    for (int q4 = 0; q4 < 4; ++q4) {
        float4 a = pp[q4];
        pv[q4 * 4] = a.x; pv[q4 * 4 + 1] = a.y; pv[q4 * 4 + 2] = a.z; pv[q4 * 4 + 3] = a.w;
        float4 bq = pp[4 + q4];
        qv[q4 * 4] = bq.x; qv[q4 * 4 + 1] = bq.y; qv[q4 * 4 + 2] = bq.z; qv[q4 * 4 + 3] = bq.w;
    }
    float o[10];
#pragma unroll
    for (int j = 0; j < 10; ++j) o[j] = 0.f;
#pragma unroll
    for (int i = 0; i < 16; ++i)
#pragma unroll
        for (int j = 0; j < 10; ++j)
            o[j] += pv[i] * w2s[i * 10 + j] + qv[i] * w2s[160 + i * 10 + j];
    float* op = out + (size_t)n * 10;
    const float* hp = hrb + (size_t)n * 10;
#pragma unroll
    for (int j = 0; j < 10; ++j) op[j] = o[j] * invd + hp[j];
}

extern "C" void kernel_launch(void* const* d_in, const int* in_sizes, int n_in,
                              void* d_out, int out_size, void* d_ws, size_t ws_size,
                              hipStream_t stream)
{
    const float* x     = (const float*)d_in[0];
    const int*   ei    = (const int*)d_in[1];   // (2,E)
    const float* ea    = (const float*)d_in[2]; // (E,1)
    const float* W1    = (const float*)d_in[3]; // (2,128,16)
    const float* root1 = (const float*)d_in[4]; // (128,16)
    const float* b1    = (const float*)d_in[5]; // (16,)
    const float* W2    = (const float*)d_in[6]; // (2,16,10)
    const float* root2 = (const float*)d_in[7]; // (16,10)
    const float* b2    = (const float*)d_in[8]; // (10,)
    float* out = (float*)d_out;

    int N = in_sizes[0] / 128;
    int E = in_sizes[2];
    int nbuk = (N + BNODES - 1) / BNODES;   // 782

    // workspace ~49.2 MB (r3 proved <=52.4 safe; r4 failed at 53.2):
    //   staging 15.2MB | buf32 N*32f (h01i N*16u32, then pq) | xr N*16f
    //   agg1 N*16f | hrb N*10f | hb N*16 bf16 | degf/cnt/roff N | gcur
    char* ws = (char*)d_ws;
    int2*  staging = (int2*)ws;
    float* buf32 = (float*)(ws + (size_t)nbuk * CAP * 8);
    unsigned int* h01i = (unsigned int*)buf32;           // N*16 u32 (first half)
    float* pq    = buf32;                                // N*32 f (after gather1)
    float* xr    = buf32 + (size_t)N * 32;
    float* agg1  = xr   + (size_t)N * 16;
    float* hrb   = agg1 + (size_t)N * 16;
    unsigned short* hb = (unsigned short*)(hrb + (size_t)N * 10);  // N*16 bf16
    float* degf  = (float*)(hb + (size_t)N * 16);
    int*   cnt   = (int*)(degf + N);
    int*   roff  = cnt  + N;
    int*   gcur  = roff + N;

    int nb_n = (N + 255) / 256;
    int nb_e16 = (N * 16 + 255) / 256;
    int gemmBlocks = (N + 127) / 128;                  // 782
    int binBlocks  = (E + CHUNK - 1) / CHUNK;          // 782
    int mixBlocks  = 2 * max(gemmBlocks, binBlocks);

    hipMemsetAsync(gcur, 0, (size_t)nbuk * sizeof(int), stream);

    phase1_kernel   <<<mixBlocks, 256, 0, stream>>>(
        x, W1, root1, h01i, xr, ei, ea, gcur, staging, N, E, nbuk, gemmBlocks);
    csr_build_kernel<<<nbuk, 256, 0, stream>>>(staging, gcur, roff, cnt, degf, N);
    gather1_kernel  <<<nb_e16, 256, 0, stream>>>(staging, roff, cnt, h01i, agg1, N);
    finalize1_kernel<<<nb_n, 256, 0, stream>>>(agg1, degf, xr, b1, root2, b2, hb, hrb, N);
    gather2_kernel  <<<nb_e16, 256, 0, stream>>>(staging, roff, cnt, hb, pq, N);
    finalize2_kernel<<<nb_n, 256, 0, stream>>>(pq, degf, hrb, W2, out, N);
}

// Round 11
// 148.855 us; speedup vs baseline: 1.3100x; 1.0629x over previous
//
#include <hip/hip_runtime.h>
#include <math.h>

// ---------------------------------------------------------------------------
// spline_net r10: CHUNK back to 4096 (r7's 2048 halved bin run-length ->
// write amp, phase1 WRITE 62MB), gemm k-unroll 4 under __launch_bounds__(256,4)
// (VGPR cap 128 stops the r7/r8 spill pattern while allowing 4 x-loads in
// flight), and finalize1/finalize2 FUSED into the gathers via 16-lane
// shfl_xor butterfly (agg1+pq buffers and 2 dispatches eliminated).
// N=100000, F_IN=128, HID=16, C=10, E=1600000
// ---------------------------------------------------------------------------

#define SHIFT    7            // 128 nodes per bucket
#define BNODES   128
#define NBUK_MAX 800          // supports N <= 102400
#define CAP      2432         // bucket capacity; mean 2046, sigma ~45 -> +8.5σ
#define CHUNK    4096         // edges per bin block (r10: back to r6 value)

__device__ __forceinline__ unsigned short f2bf(float f) {
    unsigned int u = __float_as_uint(f);
    u += 0x7FFF + ((u >> 16) & 1);        // round to nearest even
    return (unsigned short)(u >> 16);
}

// ---- fused phase 1: gemm part (LDS weights, permuted cols) + bin part ------
// LDS col order per k: [0:8)=W1[0][:,0:8) [8:16)=W1[1][:,0:8) [16:24)=root1[:,0:8)
//   [24:32)=W1[0][:,8:16) [32:40)=W1[1][:,8:16) [40:48)=root1[:,8:16)

__device__ __forceinline__ void gemm_part(
    float* __restrict__ Ws, int gb, int tid,
    const float* __restrict__ x, const float* __restrict__ W1,
    const float* __restrict__ root1, unsigned int* __restrict__ h01i,
    float* __restrict__ xr, int N)
{
    for (int idx = tid; idx < 128 * 48; idx += 256) {
        int k = idx / 48, j = idx % 48;
        int grp = j >> 3, t = j & 7;
        float v;
        switch (grp) {
            case 0: v = W1[k * 16 + t];            break;
            case 1: v = W1[2048 + k * 16 + t];     break;
            case 2: v = root1[k * 16 + t];         break;
            case 3: v = W1[k * 16 + 8 + t];        break;
            case 4: v = W1[2048 + k * 16 + 8 + t]; break;
            default: v = root1[k * 16 + 8 + t];    break;
        }
        Ws[idx] = v;
    }
    __syncthreads();
    int nl   = tid >> 1;          // node within block
    int half = tid & 1;           // channel group 0-7 / 8-15
    int n = gb * 128 + nl;
    if (n >= N) return;

    float acc[24];
#pragma unroll
    for (int j = 0; j < 24; ++j) acc[j] = 0.f;

    const float4* xrow = (const float4*)(x + (size_t)n * 128);
    const float4* wbase = (const float4*)(Ws + half * 24);
#pragma unroll 4
    for (int k4 = 0; k4 < 32; ++k4) {
        float4 xv = xrow[k4];
        float xs[4] = {xv.x, xv.y, xv.z, xv.w};
#pragma unroll
        for (int kk = 0; kk < 4; ++kk) {
            float xk = xs[kk];
            const float4* w4 = wbase + ((k4 * 4 + kk) * 48) / 4;
#pragma unroll
            for (int q = 0; q < 6; ++q) {
                float4 wv = w4[q];
                acc[q * 4 + 0] += xk * wv.x;
                acc[q * 4 + 1] += xk * wv.y;
                acc[q * 4 + 2] += xk * wv.z;
                acc[q * 4 + 3] += xk * wv.w;
            }
        }
    }
    // acc[0..7]=h0[ch], acc[8..15]=h1[ch], acc[16..23]=xr[ch], ch=half*8+t
    int cb = half * 8;
#pragma unroll
    for (int t = 0; t < 8; ++t)
        h01i[(size_t)n * 16 + cb + t] =
            (unsigned int)f2bf(acc[t]) | ((unsigned int)f2bf(acc[8 + t]) << 16);
#pragma unroll
    for (int t = 0; t < 8; ++t)
        xr[(size_t)n * 16 + cb + t] = acc[16 + t];
}

__device__ __forceinline__ void bin_part(
    int* __restrict__ smem, int bb, int tid,
    const int* __restrict__ ei, const float* __restrict__ ea,
    int* __restrict__ gcur, int2* __restrict__ staging, int E, int nbuk)
{
    int* bcnt  = smem;                  // NBUK_MAX
    int* gbase = bcnt + NBUK_MAX;       // NBUK_MAX
    for (int i = tid; i < nbuk; i += 256) bcnt[i] = 0;
    __syncthreads();

    int base = bb * CHUNK;
    int lrank[16];
#pragma unroll
    for (int i = 0; i < 16; ++i) {
        int e = base + i * 256 + tid;
        lrank[i] = 0;
        if (e < E) lrank[i] = atomicAdd(&bcnt[ei[E + e] >> SHIFT], 1);
    }
    __syncthreads();
    for (int b = tid; b < nbuk; b += 256) {
        int c = bcnt[b];
        gbase[b] = c ? atomicAdd(&gcur[b], c) : 0;
    }
    __syncthreads();
#pragma unroll
    for (int i = 0; i < 16; ++i) {
        int e = base + i * 256 + tid;
        if (e < E) {
            int s = ei[e];
            int d = ei[E + e];
            int b = d >> SHIFT;
            int p = gbase[b] + lrank[i];
            if (p < CAP)
                staging[(size_t)b * CAP + p] =
                    make_int2(s | ((d & (BNODES - 1)) << 17), __float_as_int(ea[e]));
        }
    }
}

// even blockIdx -> gemm block, odd -> bin block
__global__ __launch_bounds__(256, 4) void phase1_kernel(
    const float* __restrict__ x, const float* __restrict__ W1,
    const float* __restrict__ root1, unsigned int* __restrict__ h01i,
    float* __restrict__ xr,
    const int* __restrict__ ei, const float* __restrict__ ea,
    int* __restrict__ gcur, int2* __restrict__ staging,
    int N, int E, int nbuk, int gemmBlocks, int binBlocks)
{
    __shared__ float smem[128 * 48];   // gemm Ws (24.6KB) | bin counters (6.4KB)
    int tid = threadIdx.x;
    int bid = blockIdx.x;
    int sub = bid >> 1;
    if ((bid & 1) == 0) {
        if (sub < gemmBlocks)
            gemm_part(smem, sub, tid, x, W1, root1, h01i, xr, N);
    } else {
        if (sub < binBlocks)
            bin_part((int*)smem, sub, tid, ei, ea, gcur, staging, E, nbuk);
    }
}

// In-place per-bucket counting sort (node-sorted CSR inside the bucket).
__global__ __launch_bounds__(256) void csr_build_kernel(
    int2* __restrict__ staging, const int* __restrict__ gcur,
    int* __restrict__ roff, int* __restrict__ cnt, int N)
{
    __shared__ int2 rin[CAP];
    __shared__ int2 rout[CAP];
    __shared__ int hist[BNODES];
    __shared__ int sscan[BNODES];
    __shared__ int wcur[BNODES];
    int tid = threadIdx.x;
    int b = blockIdx.x;
    int m = gcur[b];
    if (m > CAP) m = CAP;
    int2* sp = staging + (size_t)b * CAP;

    if (tid < BNODES) { hist[tid] = 0; wcur[tid] = 0; }
    __syncthreads();
    for (int k = tid; k < m; k += 256) {
        int2 r = sp[k];
        rin[k] = r;
        atomicAdd(&hist[r.x >> 17], 1);
    }
    __syncthreads();
    if (tid < BNODES) sscan[tid] = hist[tid];
    __syncthreads();
    for (int off = 1; off < BNODES; off <<= 1) {
        int t = (tid < BNODES && tid >= off) ? sscan[tid - off] : 0;
        __syncthreads();
        if (tid < BNODES) sscan[tid] += t;
        __syncthreads();
    }
    for (int k = tid; k < m; k += 256) {
        int2 r = rin[k];
        int dl = r.x >> 17;
        int pos = (sscan[dl] - hist[dl]) + atomicAdd(&wcur[dl], 1);
        rout[pos] = make_int2(r.x & 0x1FFFF, r.y);
    }
    __syncthreads();
    for (int k = tid; k < m; k += 256) sp[k] = rout[k];
    if (tid < BNODES) {
        int n = b * BNODES + tid;
        if (n < N) {
            roff[n] = b * CAP + (sscan[tid] - hist[tid]);
            cnt[n]  = hist[tid];
        }
    }
}

// Fused layer-1 gather + finalize: 16 lanes/node, lane c owns channel c.
// acc -> h = elu(acc/deg + xr + b1) -> hb (bf16); hrb = h@root2 + b2 via
// 16-lane shfl_xor butterfly.
__global__ __launch_bounds__(256) void gather1f_kernel(
    const int2* __restrict__ staging, const int* __restrict__ roff,
    const int* __restrict__ cnt, const unsigned int* __restrict__ h01i,
    const float* __restrict__ xr, const float* __restrict__ b1,
    const float* __restrict__ root2, const float* __restrict__ b2,
    unsigned short* __restrict__ hb, float* __restrict__ hrb, int N)
{
    __shared__ float r2s[160];
    __shared__ float b1s[16];
    __shared__ float b2s[10];
    int tid = threadIdx.x;
    if (tid < 160) r2s[tid] = root2[tid];
    if (tid < 16)  b1s[tid] = b1[tid];
    if (tid < 10)  b2s[tid] = b2[tid];
    __syncthreads();
    int t = blockIdx.x * 256 + tid;
    int n = t >> 4;
    int c = t & 15;
    if (n >= N) return;
    int start = roff[n];
    int m = cnt[n];
    float acc = 0.f;
#pragma unroll 2
    for (int k = 0; k < m; ++k) {
        int2 r = staging[(size_t)start + k];
        float w = __int_as_float(r.y);
        unsigned int v = h01i[(size_t)r.x * 16 + c];
        float a  = __uint_as_float(v << 16);            // h0 (lo bf16)
        float bb = __uint_as_float(v & 0xFFFF0000u);    // h1 (hi bf16)
        acc += a + w * (bb - a);
    }
    float invd = 1.0f / fmaxf((float)m, 1.0f);
    float hv = acc * invd + xr[(size_t)n * 16 + c] + b1s[c];
    hv = hv > 0.f ? hv : expm1f(hv);
    hb[(size_t)n * 16 + c] = f2bf(hv);

    float r[10];
#pragma unroll
    for (int j = 0; j < 10; ++j) r[j] = hv * r2s[c * 10 + j];
#pragma unroll
    for (int off = 1; off < 16; off <<= 1) {
#pragma unroll
        for (int j = 0; j < 10; ++j) r[j] += __shfl_xor(r[j], off);
    }
    if (c == 0) {
        float* hp = hrb + (size_t)n * 10;
#pragma unroll
        for (int j = 0; j < 10; ++j) hp[j] = r[j] + b2s[j];
    }
}

// Fused layer-2 gather + finalize: p,q per lane -> out = (p@W2[0]+q@W2[1])/deg
// + hrb via butterfly.
__global__ __launch_bounds__(256) void gather2f_kernel(
    const int2* __restrict__ staging, const int* __restrict__ roff,
    const int* __restrict__ cnt, const unsigned short* __restrict__ hb,
    const float* __restrict__ hrb, const float* __restrict__ W2,
    float* __restrict__ out, int N)
{
    __shared__ float w2s[320];
    int tid = threadIdx.x;
    for (int idx = tid; idx < 320; idx += 256) w2s[idx] = W2[idx];
    __syncthreads();
    int t = blockIdx.x * 256 + tid;
    int n = t >> 4;
    int c = t & 15;
    if (n >= N) return;
    int start = roff[n];
    int m = cnt[n];
    float p = 0.f, q = 0.f;
#pragma unroll 2
    for (int k = 0; k < m; ++k) {
        int2 r = staging[(size_t)start + k];
        float w = __int_as_float(r.y);
        float v = __uint_as_float(((unsigned int)hb[(size_t)r.x * 16 + c]) << 16);
        p += (1.f - w) * v;
        q += w * v;
    }
    float invd = 1.0f / fmaxf((float)m, 1.0f);
    float o[10];
#pragma unroll
    for (int j = 0; j < 10; ++j)
        o[j] = p * w2s[c * 10 + j] + q * w2s[160 + c * 10 + j];
#pragma unroll
    for (int off = 1; off < 16; off <<= 1) {
#pragma unroll
        for (int j = 0; j < 10; ++j) o[j] += __shfl_xor(o[j], off);
    }
    if (c == 0) {
        float* op = out + (size_t)n * 10;
        const float* hp = hrb + (size_t)n * 10;
#pragma unroll
        for (int j = 0; j < 10; ++j) op[j] = o[j] * invd + hp[j];
    }
}

extern "C" void kernel_launch(void* const* d_in, const int* in_sizes, int n_in,
                              void* d_out, int out_size, void* d_ws, size_t ws_size,
                              hipStream_t stream)
{
    const float* x     = (const float*)d_in[0];
    const int*   ei    = (const int*)d_in[1];   // (2,E)
    const float* ea    = (const float*)d_in[2]; // (E,1)
    const float* W1    = (const float*)d_in[3]; // (2,128,16)
    const float* root1 = (const float*)d_in[4]; // (128,16)
    const float* b1    = (const float*)d_in[5]; // (16,)
    const float* W2    = (const float*)d_in[6]; // (2,16,10)
    const float* root2 = (const float*)d_in[7]; // (16,10)
    const float* b2    = (const float*)d_in[8]; // (10,)
    float* out = (float*)d_out;

    int N = in_sizes[0] / 128;
    int E = in_sizes[2];
    int nbuk = (N + BNODES - 1) / BNODES;   // 782

    // workspace ~36 MB:
    //   staging 15.2MB | h01i N*16 u32 | xr N*16 f | hrb N*10 f
    //   hb N*16 bf16 | cnt N | roff N | gcur nbuk
    char* ws = (char*)d_ws;
    int2*  staging = (int2*)ws;
    unsigned int* h01i = (unsigned int*)(ws + (size_t)nbuk * CAP * 8);
    float* xr    = (float*)(h01i + (size_t)N * 16);
    float* hrb   = xr + (size_t)N * 16;
    unsigned short* hb = (unsigned short*)(hrb + (size_t)N * 10);
    int*   cnt   = (int*)(hb + (size_t)N * 16);
    int*   roff  = cnt + N;
    int*   gcur  = roff + N;

    int nb_e16 = (N * 16 + 255) / 256;
    int gemmBlocks = (N + 127) / 128;                  // 782
    int binBlocks  = (E + CHUNK - 1) / CHUNK;          // 391
    int mixBlocks  = 2 * ((gemmBlocks > binBlocks) ? gemmBlocks : binBlocks);

    hipMemsetAsync(gcur, 0, (size_t)nbuk * sizeof(int), stream);

    phase1_kernel   <<<mixBlocks, 256, 0, stream>>>(
        x, W1, root1, h01i, xr, ei, ea, gcur, staging, N, E, nbuk,
        gemmBlocks, binBlocks);
    csr_build_kernel<<<nbuk, 256, 0, stream>>>(staging, gcur, roff, cnt, N);
    gather1f_kernel <<<nb_e16, 256, 0, stream>>>(staging, roff, cnt, h01i, xr,
                                                 b1, root2, b2, hb, hrb, N);
    gather2f_kernel <<<nb_e16, 256, 0, stream>>>(staging, roff, cnt, hb, hrb,
                                                 W2, out, N);
}

// Round 12
// 148.546 us; speedup vs baseline: 1.3128x; 1.0021x over previous
//
#include <hip/hip_runtime.h>
#include <math.h>

// ---------------------------------------------------------------------------
// spline_net r10: CHUNK back to 4096 (r7's 2048 halved bin run-length ->
// write amp, phase1 WRITE 62MB), gemm k-unroll 4 under __launch_bounds__(256,4)
// (VGPR cap 128 stops the r7/r8 spill pattern while allowing 4 x-loads in
// flight), and finalize1/finalize2 FUSED into the gathers via 16-lane
// shfl_xor butterfly (agg1+pq buffers and 2 dispatches eliminated).
// N=100000, F_IN=128, HID=16, C=10, E=1600000
// ---------------------------------------------------------------------------

#define SHIFT    7            // 128 nodes per bucket
#define BNODES   128
#define NBUK_MAX 800          // supports N <= 102400
#define CAP      2432         // bucket capacity; mean 2046, sigma ~45 -> +8.5σ
#define CHUNK    4096         // edges per bin block (r10: back to r6 value)

__device__ __forceinline__ unsigned short f2bf(float f) {
    unsigned int u = __float_as_uint(f);
    u += 0x7FFF + ((u >> 16) & 1);        // round to nearest even
    return (unsigned short)(u >> 16);
}

// ---- fused phase 1: gemm part (LDS weights, permuted cols) + bin part ------
// LDS col order per k: [0:8)=W1[0][:,0:8) [8:16)=W1[1][:,0:8) [16:24)=root1[:,0:8)
//   [24:32)=W1[0][:,8:16) [32:40)=W1[1][:,8:16) [40:48)=root1[:,8:16)

__device__ __forceinline__ void gemm_part(
    float* __restrict__ Ws, int gb, int tid,
    const float* __restrict__ x, const float* __restrict__ W1,
    const float* __restrict__ root1, unsigned int* __restrict__ h01i,
    float* __restrict__ xr, int N)
{
    for (int idx = tid; idx < 128 * 48; idx += 256) {
        int k = idx / 48, j = idx % 48;
        int grp = j >> 3, t = j & 7;
        float v;
        switch (grp) {
            case 0: v = W1[k * 16 + t];            break;
            case 1: v = W1[2048 + k * 16 + t];     break;
            case 2: v = root1[k * 16 + t];         break;
            case 3: v = W1[k * 16 + 8 + t];        break;
            case 4: v = W1[2048 + k * 16 + 8 + t]; break;
            default: v = root1[k * 16 + 8 + t];    break;
        }
        Ws[idx] = v;
    }
    __syncthreads();
    int nl   = tid >> 1;          // node within block
    int half = tid & 1;           // channel group 0-7 / 8-15
    int n = gb * 128 + nl;
    if (n >= N) return;

    float acc[24];
#pragma unroll
    for (int j = 0; j < 24; ++j) acc[j] = 0.f;

    const float4* xrow = (const float4*)(x + (size_t)n * 128);
    const float4* wbase = (const float4*)(Ws + half * 24);
#pragma unroll 4
    for (int k4 = 0; k4 < 32; ++k4) {
        float4 xv = xrow[k4];
        float xs[4] = {xv.x, xv.y, xv.z, xv.w};
#pragma unroll
        for (int kk = 0; kk < 4; ++kk) {
            float xk = xs[kk];
            const float4* w4 = wbase + ((k4 * 4 + kk) * 48) / 4;
#pragma unroll
            for (int q = 0; q < 6; ++q) {
                float4 wv = w4[q];
                acc[q * 4 + 0] += xk * wv.x;
                acc[q * 4 + 1] += xk * wv.y;
                acc[q * 4 + 2] += xk * wv.z;
                acc[q * 4 + 3] += xk * wv.w;
            }
        }
    }
    // acc[0..7]=h0[ch], acc[8..15]=h1[ch], acc[16..23]=xr[ch], ch=half*8+t
    int cb = half * 8;
#pragma unroll
    for (int t = 0; t < 8; ++t)
        h01i[(size_t)n * 16 + cb + t] =
            (unsigned int)f2bf(acc[t]) | ((unsigned int)f2bf(acc[8 + t]) << 16);
#pragma unroll
    for (int t = 0; t < 8; ++t)
        xr[(size_t)n * 16 + cb + t] = acc[16 + t];
}

__device__ __forceinline__ void bin_part(
    int* __restrict__ smem, int bb, int tid,
    const int* __restrict__ ei, const float* __restrict__ ea,
    int* __restrict__ gcur, int2* __restrict__ staging, int E, int nbuk)
{
    int* bcnt  = smem;                  // NBUK_MAX
    int* gbase = bcnt + NBUK_MAX;       // NBUK_MAX
    for (int i = tid; i < nbuk; i += 256) bcnt[i] = 0;
    __syncthreads();

    int base = bb * CHUNK;
    int lrank[16];
#pragma unroll
    for (int i = 0; i < 16; ++i) {
        int e = base + i * 256 + tid;
        lrank[i] = 0;
        if (e < E) lrank[i] = atomicAdd(&bcnt[ei[E + e] >> SHIFT], 1);
    }
    __syncthreads();
    for (int b = tid; b < nbuk; b += 256) {
        int c = bcnt[b];
        gbase[b] = c ? atomicAdd(&gcur[b], c) : 0;
    }
    __syncthreads();
#pragma unroll
    for (int i = 0; i < 16; ++i) {
        int e = base + i * 256 + tid;
        if (e < E) {
            int s = ei[e];
            int d = ei[E + e];
            int b = d >> SHIFT;
            int p = gbase[b] + lrank[i];
            if (p < CAP)
                staging[(size_t)b * CAP + p] =
                    make_int2(s | ((d & (BNODES - 1)) << 17), __float_as_int(ea[e]));
        }
    }
}

// even blockIdx -> gemm block, odd -> bin block
__global__ __launch_bounds__(256, 4) void phase1_kernel(
    const float* __restrict__ x, const float* __restrict__ W1,
    const float* __restrict__ root1, unsigned int* __restrict__ h01i,
    float* __restrict__ xr,
    const int* __restrict__ ei, const float* __restrict__ ea,
    int* __restrict__ gcur, int2* __restrict__ staging,
    int N, int E, int nbuk, int gemmBlocks, int binBlocks)
{
    __shared__ float smem[128 * 48];   // gemm Ws (24.6KB) | bin counters (6.4KB)
    int tid = threadIdx.x;
    int bid = blockIdx.x;
    int sub = bid >> 1;
    if ((bid & 1) == 0) {
        if (sub < gemmBlocks)
            gemm_part(smem, sub, tid, x, W1, root1, h01i, xr, N);
    } else {
        if (sub < binBlocks)
            bin_part((int*)smem, sub, tid, ei, ea, gcur, staging, E, nbuk);
    }
}

// In-place per-bucket counting sort (node-sorted CSR inside the bucket).
__global__ __launch_bounds__(256) void csr_build_kernel(
    int2* __restrict__ staging, const int* __restrict__ gcur,
    int* __restrict__ roff, int* __restrict__ cnt, int N)
{
    __shared__ int2 rin[CAP];
    __shared__ int2 rout[CAP];
    __shared__ int hist[BNODES];
    __shared__ int sscan[BNODES];
    __shared__ int wcur[BNODES];
    int tid = threadIdx.x;
    int b = blockIdx.x;
    int m = gcur[b];
    if (m > CAP) m = CAP;
    int2* sp = staging + (size_t)b * CAP;

    if (tid < BNODES) { hist[tid] = 0; wcur[tid] = 0; }
    __syncthreads();
    for (int k = tid; k < m; k += 256) {
        int2 r = sp[k];
        rin[k] = r;
        atomicAdd(&hist[r.x >> 17], 1);
    }
    __syncthreads();
    if (tid < BNODES) sscan[tid] = hist[tid];
    __syncthreads();
    for (int off = 1; off < BNODES; off <<= 1) {
        int t = (tid < BNODES && tid >= off) ? sscan[tid - off] : 0;
        __syncthreads();
        if (tid < BNODES) sscan[tid] += t;
        __syncthreads();
    }
    for (int k = tid; k < m; k += 256) {
        int2 r = rin[k];
        int dl = r.x >> 17;
        int pos = (sscan[dl] - hist[dl]) + atomicAdd(&wcur[dl], 1);
        rout[pos] = make_int2(r.x & 0x1FFFF, r.y);
    }
    __syncthreads();
    for (int k = tid; k < m; k += 256) sp[k] = rout[k];
    if (tid < BNODES) {
        int n = b * BNODES + tid;
        if (n < N) {
            roff[n] = b * CAP + (sscan[tid] - hist[tid]);
            cnt[n]  = hist[tid];
        }
    }
}

// Fused layer-1 gather + finalize: 16 lanes/node, lane c owns channel c.
// acc -> h = elu(acc/deg + xr + b1) -> hb (bf16); hrb = h@root2 + b2 via
// 16-lane shfl_xor butterfly.
__global__ __launch_bounds__(256) void gather1f_kernel(
    const int2* __restrict__ staging, const int* __restrict__ roff,
    const int* __restrict__ cnt, const unsigned int* __restrict__ h01i,
    const float* __restrict__ xr, const float* __restrict__ b1,
    const float* __restrict__ root2, const float* __restrict__ b2,
    unsigned short* __restrict__ hb, float* __restrict__ hrb, int N)
{
    __shared__ float r2s[160];
    __shared__ float b1s[16];
    __shared__ float b2s[10];
    int tid = threadIdx.x;
    if (tid < 160) r2s[tid] = root2[tid];
    if (tid < 16)  b1s[tid] = b1[tid];
    if (tid < 10)  b2s[tid] = b2[tid];
    __syncthreads();
    int t = blockIdx.x * 256 + tid;
    int n = t >> 4;
    int c = t & 15;
    if (n >= N) return;
    int start = roff[n];
    int m = cnt[n];
    float acc = 0.f;
#pragma unroll 2
    for (int k = 0; k < m; ++k) {
        int2 r = staging[(size_t)start + k];
        float w = __int_as_float(r.y);
        unsigned int v = h01i[(size_t)r.x * 16 + c];
        float a  = __uint_as_float(v << 16);            // h0 (lo bf16)
        float bb = __uint_as_float(v & 0xFFFF0000u);    // h1 (hi bf16)
        acc += a + w * (bb - a);
    }
    float invd = 1.0f / fmaxf((float)m, 1.0f);
    float hv = acc * invd + xr[(size_t)n * 16 + c] + b1s[c];
    hv = hv > 0.f ? hv : expm1f(hv);
    hb[(size_t)n * 16 + c] = f2bf(hv);

    float r[10];
#pragma unroll
    for (int j = 0; j < 10; ++j) r[j] = hv * r2s[c * 10 + j];
#pragma unroll
    for (int off = 1; off < 16; off <<= 1) {
#pragma unroll
        for (int j = 0; j < 10; ++j) r[j] += __shfl_xor(r[j], off);
    }
    if (c == 0) {
        float* hp = hrb + (size_t)n * 10;
#pragma unroll
        for (int j = 0; j < 10; ++j) hp[j] = r[j] + b2s[j];
    }
}

// Fused layer-2 gather + finalize: p,q per lane -> out = (p@W2[0]+q@W2[1])/deg
// + hrb via butterfly.
__global__ __launch_bounds__(256) void gather2f_kernel(
    const int2* __restrict__ staging, const int* __restrict__ roff,
    const int* __restrict__ cnt, const unsigned short* __restrict__ hb,
    const float* __restrict__ hrb, const float* __restrict__ W2,
    float* __restrict__ out, int N)
{
    __shared__ float w2s[320];
    int tid = threadIdx.x;
    for (int idx = tid; idx < 320; idx += 256) w2s[idx] = W2[idx];
    __syncthreads();
    int t = blockIdx.x * 256 + tid;
    int n = t >> 4;
    int c = t & 15;
    if (n >= N) return;
    int start = roff[n];
    int m = cnt[n];
    float p = 0.f, q = 0.f;
#pragma unroll 2
    for (int k = 0; k < m; ++k) {
        int2 r = staging[(size_t)start + k];
        float w = __int_as_float(r.y);
        float v = __uint_as_float(((unsigned int)hb[(size_t)r.x * 16 + c]) << 16);
        p += (1.f - w) * v;
        q += w * v;
    }
    float invd = 1.0f / fmaxf((float)m, 1.0f);
    float o[10];
#pragma unroll
    for (int j = 0; j < 10; ++j)
        o[j] = p * w2s[c * 10 + j] + q * w2s[160 + c * 10 + j];
#pragma unroll
    for (int off = 1; off < 16; off <<= 1) {
#pragma unroll
        for (int j = 0; j < 10; ++j) o[j] += __shfl_xor(o[j], off);
    }
    if (c == 0) {
        float* op = out + (size_t)n * 10;
        const float* hp = hrb + (size_t)n * 10;
#pragma unroll
        for (int j = 0; j < 10; ++j) op[j] = o[j] * invd + hp[j];
    }
}

extern "C" void kernel_launch(void* const* d_in, const int* in_sizes, int n_in,
                              void* d_out, int out_size, void* d_ws, size_t ws_size,
                              hipStream_t stream)
{
    const float* x     = (const float*)d_in[0];
    const int*   ei    = (const int*)d_in[1];   // (2,E)
    const float* ea    = (const float*)d_in[2]; // (E,1)
    const float* W1    = (const float*)d_in[3]; // (2,128,16)
    const float* root1 = (const float*)d_in[4]; // (128,16)
    const float* b1    = (const float*)d_in[5]; // (16,)
    const float* W2    = (const float*)d_in[6]; // (2,16,10)
    const float* root2 = (const float*)d_in[7]; // (16,10)
    const float* b2    = (const float*)d_in[8]; // (10,)
    float* out = (float*)d_out;

    int N = in_sizes[0] / 128;
    int E = in_sizes[2];
    int nbuk = (N + BNODES - 1) / BNODES;   // 782

    // workspace ~36 MB:
    //   staging 15.2MB | h01i N*16 u32 | xr N*16 f | hrb N*10 f
    //   hb N*16 bf16 | cnt N | roff N | gcur nbuk
    char* ws = (char*)d_ws;
    int2*  staging = (int2*)ws;
    unsigned int* h01i = (unsigned int*)(ws + (size_t)nbuk * CAP * 8);
    float* xr    = (float*)(h01i + (size_t)N * 16);
    float* hrb   = xr + (size_t)N * 16;
    unsigned short* hb = (unsigned short*)(hrb + (size_t)N * 10);
    int*   cnt   = (int*)(hb + (size_t)N * 16);
    int*   roff  = cnt + N;
    int*   gcur  = roff + N;

    int nb_e16 = (N * 16 + 255) / 256;
    int gemmBlocks = (N + 127) / 128;                  // 782
    int binBlocks  = (E + CHUNK - 1) / CHUNK;          // 391
    int mixBlocks  = 2 * ((gemmBlocks > binBlocks) ? gemmBlocks : binBlocks);

    hipMemsetAsync(gcur, 0, (size_t)nbuk * sizeof(int), stream);

    phase1_kernel   <<<mixBlocks, 256, 0, stream>>>(
        x, W1, root1, h01i, xr, ei, ea, gcur, staging, N, E, nbuk,
        gemmBlocks, binBlocks);
    csr_build_kernel<<<nbuk, 256, 0, stream>>>(staging, gcur, roff, cnt, N);
    gather1f_kernel <<<nb_e16, 256, 0, stream>>>(staging, roff, cnt, h01i, xr,
                                                 b1, root2, b2, hb, hrb, N);
    gather2f_kernel <<<nb_e16, 256, 0, stream>>>(staging, roff, cnt, hb, hrb,
                                                 W2, out, N);
}

// Round 13
// 148.012 us; speedup vs baseline: 1.3175x; 1.0036x over previous
//
#include <hip/hip_runtime.h>
#include <math.h>

// ---------------------------------------------------------------------------
// spline_net r10: CHUNK back to 4096 (r7's 2048 halved bin run-length ->
// write amp, phase1 WRITE 62MB), gemm k-unroll 4 under __launch_bounds__(256,4)
// (VGPR cap 128 stops the r7/r8 spill pattern while allowing 4 x-loads in
// flight), and finalize1/finalize2 FUSED into the gathers via 16-lane
// shfl_xor butterfly (agg1+pq buffers and 2 dispatches eliminated).
// N=100000, F_IN=128, HID=16, C=10, E=1600000
// ---------------------------------------------------------------------------

#define SHIFT    7            // 128 nodes per bucket
#define BNODES   128
#define NBUK_MAX 800          // supports N <= 102400
#define CAP      2432         // bucket capacity; mean 2046, sigma ~45 -> +8.5σ
#define CHUNK    4096         // edges per bin block (r10: back to r6 value)

__device__ __forceinline__ unsigned short f2bf(float f) {
    unsigned int u = __float_as_uint(f);
    u += 0x7FFF + ((u >> 16) & 1);        // round to nearest even
    return (unsigned short)(u >> 16);
}

// ---- fused phase 1: gemm part (LDS weights, permuted cols) + bin part ------
// LDS col order per k: [0:8)=W1[0][:,0:8) [8:16)=W1[1][:,0:8) [16:24)=root1[:,0:8)
//   [24:32)=W1[0][:,8:16) [32:40)=W1[1][:,8:16) [40:48)=root1[:,8:16)

__device__ __forceinline__ void gemm_part(
    float* __restrict__ Ws, int gb, int tid,
    const float* __restrict__ x, const float* __restrict__ W1,
    const float* __restrict__ root1, unsigned int* __restrict__ h01i,
    float* __restrict__ xr, int N)
{
    for (int idx = tid; idx < 128 * 48; idx += 256) {
        int k = idx / 48, j = idx % 48;
        int grp = j >> 3, t = j & 7;
        float v;
        switch (grp) {
            case 0: v = W1[k * 16 + t];            break;
            case 1: v = W1[2048 + k * 16 + t];     break;
            case 2: v = root1[k * 16 + t];         break;
            case 3: v = W1[k * 16 + 8 + t];        break;
            case 4: v = W1[2048 + k * 16 + 8 + t]; break;
            default: v = root1[k * 16 + 8 + t];    break;
        }
        Ws[idx] = v;
    }
    __syncthreads();
    int nl   = tid >> 1;          // node within block
    int half = tid & 1;           // channel group 0-7 / 8-15
    int n = gb * 128 + nl;
    if (n >= N) return;

    float acc[24];
#pragma unroll
    for (int j = 0; j < 24; ++j) acc[j] = 0.f;

    const float4* xrow = (const float4*)(x + (size_t)n * 128);
    const float4* wbase = (const float4*)(Ws + half * 24);
#pragma unroll 4
    for (int k4 = 0; k4 < 32; ++k4) {
        float4 xv = xrow[k4];
        float xs[4] = {xv.x, xv.y, xv.z, xv.w};
#pragma unroll
        for (int kk = 0; kk < 4; ++kk) {
            float xk = xs[kk];
            const float4* w4 = wbase + ((k4 * 4 + kk) * 48) / 4;
#pragma unroll
            for (int q = 0; q < 6; ++q) {
                float4 wv = w4[q];
                acc[q * 4 + 0] += xk * wv.x;
                acc[q * 4 + 1] += xk * wv.y;
                acc[q * 4 + 2] += xk * wv.z;
                acc[q * 4 + 3] += xk * wv.w;
            }
        }
    }
    // acc[0..7]=h0[ch], acc[8..15]=h1[ch], acc[16..23]=xr[ch], ch=half*8+t
    int cb = half * 8;
#pragma unroll
    for (int t = 0; t < 8; ++t)
        h01i[(size_t)n * 16 + cb + t] =
            (unsigned int)f2bf(acc[t]) | ((unsigned int)f2bf(acc[8 + t]) << 16);
#pragma unroll
    for (int t = 0; t < 8; ++t)
        xr[(size_t)n * 16 + cb + t] = acc[16 + t];
}

__device__ __forceinline__ void bin_part(
    int* __restrict__ smem, int bb, int tid,
    const int* __restrict__ ei, const float* __restrict__ ea,
    int* __restrict__ gcur, int2* __restrict__ staging, int E, int nbuk)
{
    int* bcnt  = smem;                  // NBUK_MAX
    int* gbase = bcnt + NBUK_MAX;       // NBUK_MAX
    for (int i = tid; i < nbuk; i += 256) bcnt[i] = 0;
    __syncthreads();

    int base = bb * CHUNK;
    int lrank[16];
#pragma unroll
    for (int i = 0; i < 16; ++i) {
        int e = base + i * 256 + tid;
        lrank[i] = 0;
        if (e < E) lrank[i] = atomicAdd(&bcnt[ei[E + e] >> SHIFT], 1);
    }
    __syncthreads();
    for (int b = tid; b < nbuk; b += 256) {
        int c = bcnt[b];
        gbase[b] = c ? atomicAdd(&gcur[b], c) : 0;
    }
    __syncthreads();
#pragma unroll
    for (int i = 0; i < 16; ++i) {
        int e = base + i * 256 + tid;
        if (e < E) {
            int s = ei[e];
            int d = ei[E + e];
            int b = d >> SHIFT;
            int p = gbase[b] + lrank[i];
            if (p < CAP)
                staging[(size_t)b * CAP + p] =
                    make_int2(s | ((d & (BNODES - 1)) << 17), __float_as_int(ea[e]));
        }
    }
}

// even blockIdx -> gemm block, odd -> bin block
__global__ __launch_bounds__(256, 4) void phase1_kernel(
    const float* __restrict__ x, const float* __restrict__ W1,
    const float* __restrict__ root1, unsigned int* __restrict__ h01i,
    float* __restrict__ xr,
    const int* __restrict__ ei, const float* __restrict__ ea,
    int* __restrict__ gcur, int2* __restrict__ staging,
    int N, int E, int nbuk, int gemmBlocks, int binBlocks)
{
    __shared__ float smem[128 * 48];   // gemm Ws (24.6KB) | bin counters (6.4KB)
    int tid = threadIdx.x;
    int bid = blockIdx.x;
    int sub = bid >> 1;
    if ((bid & 1) == 0) {
        if (sub < gemmBlocks)
            gemm_part(smem, sub, tid, x, W1, root1, h01i, xr, N);
    } else {
        if (sub < binBlocks)
            bin_part((int*)smem, sub, tid, ei, ea, gcur, staging, E, nbuk);
    }
}

// In-place per-bucket counting sort (node-sorted CSR inside the bucket).
__global__ __launch_bounds__(256) void csr_build_kernel(
    int2* __restrict__ staging, const int* __restrict__ gcur,
    int* __restrict__ roff, int* __restrict__ cnt, int N)
{
    __shared__ int2 rin[CAP];
    __shared__ int2 rout[CAP];
    __shared__ int hist[BNODES];
    __shared__ int sscan[BNODES];
    __shared__ int wcur[BNODES];
    int tid = threadIdx.x;
    int b = blockIdx.x;
    int m = gcur[b];
    if (m > CAP) m = CAP;
    int2* sp = staging + (size_t)b * CAP;

    if (tid < BNODES) { hist[tid] = 0; wcur[tid] = 0; }
    __syncthreads();
    for (int k = tid; k < m; k += 256) {
        int2 r = sp[k];
        rin[k] = r;
        atomicAdd(&hist[r.x >> 17], 1);
    }
    __syncthreads();
    if (tid < BNODES) sscan[tid] = hist[tid];
    __syncthreads();
    for (int off = 1; off < BNODES; off <<= 1) {
        int t = (tid < BNODES && tid >= off) ? sscan[tid - off] : 0;
        __syncthreads();
        if (tid < BNODES) sscan[tid] += t;
        __syncthreads();
    }
    for (int k = tid; k < m; k += 256) {
        int2 r = rin[k];
        int dl = r.x >> 17;
        int pos = (sscan[dl] - hist[dl]) + atomicAdd(&wcur[dl], 1);
        rout[pos] = make_int2(r.x & 0x1FFFF, r.y);
    }
    __syncthreads();
    for (int k = tid; k < m; k += 256) sp[k] = rout[k];
    if (tid < BNODES) {
        int n = b * BNODES + tid;
        if (n < N) {
            roff[n] = b * CAP + (sscan[tid] - hist[tid]);
            cnt[n]  = hist[tid];
        }
    }
}

// Fused layer-1 gather + finalize: 16 lanes/node, lane c owns channel c.
// acc -> h = elu(acc/deg + xr + b1) -> hb (bf16); hrb = h@root2 + b2 via
// 16-lane shfl_xor butterfly.
__global__ __launch_bounds__(256) void gather1f_kernel(
    const int2* __restrict__ staging, const int* __restrict__ roff,
    const int* __restrict__ cnt, const unsigned int* __restrict__ h01i,
    const float* __restrict__ xr, const float* __restrict__ b1,
    const float* __restrict__ root2, const float* __restrict__ b2,
    unsigned short* __restrict__ hb, float* __restrict__ hrb, int N)
{
    __shared__ float r2s[160];
    __shared__ float b1s[16];
    __shared__ float b2s[10];
    int tid = threadIdx.x;
    if (tid < 160) r2s[tid] = root2[tid];
    if (tid < 16)  b1s[tid] = b1[tid];
    if (tid < 10)  b2s[tid] = b2[tid];
    __syncthreads();
    int t = blockIdx.x * 256 + tid;
    int n = t >> 4;
    int c = t & 15;
    if (n >= N) return;
    int start = roff[n];
    int m = cnt[n];
    float acc = 0.f;
#pragma unroll 2
    for (int k = 0; k < m; ++k) {
        int2 r = staging[(size_t)start + k];
        float w = __int_as_float(r.y);
        unsigned int v = h01i[(size_t)r.x * 16 + c];
        float a  = __uint_as_float(v << 16);            // h0 (lo bf16)
        float bb = __uint_as_float(v & 0xFFFF0000u);    // h1 (hi bf16)
        acc += a + w * (bb - a);
    }
    float invd = 1.0f / fmaxf((float)m, 1.0f);
    float hv = acc * invd + xr[(size_t)n * 16 + c] + b1s[c];
    hv = hv > 0.f ? hv : expm1f(hv);
    hb[(size_t)n * 16 + c] = f2bf(hv);

    float r[10];
#pragma unroll
    for (int j = 0; j < 10; ++j) r[j] = hv * r2s[c * 10 + j];
#pragma unroll
    for (int off = 1; off < 16; off <<= 1) {
#pragma unroll
        for (int j = 0; j < 10; ++j) r[j] += __shfl_xor(r[j], off);
    }
    if (c == 0) {
        float* hp = hrb + (size_t)n * 10;
#pragma unroll
        for (int j = 0; j < 10; ++j) hp[j] = r[j] + b2s[j];
    }
}

// Fused layer-2 gather + finalize: p,q per lane -> out = (p@W2[0]+q@W2[1])/deg
// + hrb via butterfly.
__global__ __launch_bounds__(256) void gather2f_kernel(
    const int2* __restrict__ staging, const int* __restrict__ roff,
    const int* __restrict__ cnt, const unsigned short* __restrict__ hb,
    const float* __restrict__ hrb, const float* __restrict__ W2,
    float* __restrict__ out, int N)
{
    __shared__ float w2s[320];
    int tid = threadIdx.x;
    for (int idx = tid; idx < 320; idx += 256) w2s[idx] = W2[idx];
    __syncthreads();
    int t = blockIdx.x * 256 + tid;
    int n = t >> 4;
    int c = t & 15;
    if (n >= N) return;
    int start = roff[n];
    int m = cnt[n];
    float p = 0.f, q = 0.f;
#pragma unroll 2
    for (int k = 0; k < m; ++k) {
        int2 r = staging[(size_t)start + k];
        float w = __int_as_float(r.y);
        float v = __uint_as_float(((unsigned int)hb[(size_t)r.x * 16 + c]) << 16);
        p += (1.f - w) * v;
        q += w * v;
    }
    float invd = 1.0f / fmaxf((float)m, 1.0f);
    float o[10];
#pragma unroll
    for (int j = 0; j < 10; ++j)
        o[j] = p * w2s[c * 10 + j] + q * w2s[160 + c * 10 + j];
#pragma unroll
    for (int off = 1; off < 16; off <<= 1) {
#pragma unroll
        for (int j = 0; j < 10; ++j) o[j] += __shfl_xor(o[j], off);
    }
    if (c == 0) {
        float* op = out + (size_t)n * 10;
        const float* hp = hrb + (size_t)n * 10;
#pragma unroll
        for (int j = 0; j < 10; ++j) op[j] = o[j] * invd + hp[j];
    }
}

extern "C" void kernel_launch(void* const* d_in, const int* in_sizes, int n_in,
                              void* d_out, int out_size, void* d_ws, size_t ws_size,
                              hipStream_t stream)
{
    const float* x     = (const float*)d_in[0];
    const int*   ei    = (const int*)d_in[1];   // (2,E)
    const float* ea    = (const float*)d_in[2]; // (E,1)
    const float* W1    = (const float*)d_in[3]; // (2,128,16)
    const float* root1 = (const float*)d_in[4]; // (128,16)
    const float* b1    = (const float*)d_in[5]; // (16,)
    const float* W2    = (const float*)d_in[6]; // (2,16,10)
    const float* root2 = (const float*)d_in[7]; // (16,10)
    const float* b2    = (const float*)d_in[8]; // (10,)
    float* out = (float*)d_out;

    int N = in_sizes[0] / 128;
    int E = in_sizes[2];
    int nbuk = (N + BNODES - 1) / BNODES;   // 782

    // workspace ~36 MB:
    //   staging 15.2MB | h01i N*16 u32 | xr N*16 f | hrb N*10 f
    //   hb N*16 bf16 | cnt N | roff N | gcur nbuk
    char* ws = (char*)d_ws;
    int2*  staging = (int2*)ws;
    unsigned int* h01i = (unsigned int*)(ws + (size_t)nbuk * CAP * 8);
    float* xr    = (float*)(h01i + (size_t)N * 16);
    float* hrb   = xr + (size_t)N * 16;
    unsigned short* hb = (unsigned short*)(hrb + (size_t)N * 10);
    int*   cnt   = (int*)(hb + (size_t)N * 16);
    int*   roff  = cnt + N;
    int*   gcur  = roff + N;

    int nb_e16 = (N * 16 + 255) / 256;
    int gemmBlocks = (N + 127) / 128;                  // 782
    int binBlocks  = (E + CHUNK - 1) / CHUNK;          // 391
    int mixBlocks  = 2 * ((gemmBlocks > binBlocks) ? gemmBlocks : binBlocks);

    hipMemsetAsync(gcur, 0, (size_t)nbuk * sizeof(int), stream);

    phase1_kernel   <<<mixBlocks, 256, 0, stream>>>(
        x, W1, root1, h01i, xr, ei, ea, gcur, staging, N, E, nbuk,
        gemmBlocks, binBlocks);
    csr_build_kernel<<<nbuk, 256, 0, stream>>>(staging, gcur, roff, cnt, N);
    gather1f_kernel <<<nb_e16, 256, 0, stream>>>(staging, roff, cnt, h01i, xr,
                                                 b1, root2, b2, hb, hrb, N);
    gather2f_kernel <<<nb_e16, 256, 0, stream>>>(staging, roff, cnt, hb, hrb,
                                                 W2, out, N);
}